// Round 6
// baseline (90.927 us; speedup 1.0000x reference)
//
#include <hip/hip_runtime.h>
#include <math.h>

#define BB 8
#define SS 4096
#define EE 128
#define HH 64
#define NT 16   // KV tiles per flash block (split-K4: 1024 keys / 64)
#define LOG2E 1.44269504088896f

typedef _Float16 f16;
typedef __attribute__((ext_vector_type(8))) _Float16 f16x8;
typedef __attribute__((ext_vector_type(4))) float f32x4;

__device__ __forceinline__ unsigned int pk2h(float a, float b) {
    return __builtin_bit_cast(unsigned int, __builtin_amdgcn_cvt_pkrtz(a, b));
}

// async global->LDS DMA, 16 B per lane. LDS dest is wave-uniform base +
// lane*16 (linear); swizzle is achieved by pre-swizzling the per-lane
// GLOBAL source address (m173 pattern / rule #21).
__device__ __forceinline__ void async_copy16(void* lds, const void* g) {
    __builtin_amdgcn_global_load_lds(
        (const __attribute__((address_space(1))) void*)g,
        (__attribute__((address_space(3))) void*)lds, 16, 0, 0);
}

// drain DMA + LDS, workgroup barrier, pin scheduler (rule #18)
__device__ __forceinline__ void vm_barrier() {
    asm volatile("s_waitcnt vmcnt(0) lgkmcnt(0)" ::: "memory");
    __builtin_amdgcn_s_barrier();
    __builtin_amdgcn_sched_barrier(0);
}

// ---------------- W transpose+convert setup ----------------
// Wt f16 [192 cols][128 e]: cols 0-63 = Wq*log2e, 64-127 = Wk, 128-191 = Wv.
__global__ __launch_bounds__(256) void wtrans_kernel(
    const float* __restrict__ Wq, const float* __restrict__ Wk,
    const float* __restrict__ Wv, f16* __restrict__ Wt)
{
    const int idx = blockIdx.x * 256 + threadIdx.x;
    if (idx >= 192 * 128) return;
    const int col = idx >> 7, e = idx & 127;
    const float v = (col < 64)  ? Wq[e * 64 + col] * LOG2E
                  : (col < 128) ? Wk[e * 64 + (col - 64)]
                                : Wv[e * 64 + (col - 128)];
    Wt[col * 128 + e] = (f16)v;
}

// ---------------- QKV projection: fp16 MFMA GEMM ----------------
// Q pre-scaled by log2e (folded into Wq/bq) -> flash softmax is exp2-native.
__global__ __launch_bounds__(256) void qkv_kernel(
    const float* __restrict__ x, const f16* __restrict__ Wt,
    const float* __restrict__ bq, const float* __restrict__ bk,
    const float* __restrict__ bv,
    f16* __restrict__ Q, f16* __restrict__ K, f16* __restrict__ Vt)
{
    __shared__ __align__(16) short xs[64 * EE];   // fp16 tile, 256 B rows
    const int tid = threadIdx.x;
    const long rowbase = (long)blockIdx.x * 64;

    {
        const float4* xg = (const float4*)(x + rowbase * EE);
#pragma unroll
        for (int j = 0; j < 8; ++j) {
            const int eidx = tid * 32 + j * 4;
            const float4 v = xg[eidx >> 2];
            unsigned long long pk =
                (unsigned long long)pk2h(v.x, v.y) |
                ((unsigned long long)pk2h(v.z, v.w) << 32);
            const int row = eidx >> 7;
            const int off = (row * 256 + (eidx & 127) * 2) ^ ((row & 7) << 4);
            *(unsigned long long*)((char*)xs + off) = pk;
        }
    }
    __syncthreads();

    const int lane = tid & 63;
    const int wid  = tid >> 6;
    const int ln15 = lane & 15;
    const int lg   = lane >> 4;

    f16x8 xa[4];
    {
        const int row = wid * 16 + ln15;
        const int swz = (row & 7) << 4;
#pragma unroll
        for (int s = 0; s < 4; ++s)
            xa[s] = *(const f16x8*)((const char*)xs + ((row * 256 + lg * 16 + s * 64) ^ swz));
    }

    f32x4 acc[12];
#pragma unroll
    for (int ct = 0; ct < 12; ++ct) acc[ct] = (f32x4){0.f, 0.f, 0.f, 0.f};

#pragma unroll
    for (int ct = 0; ct < 12; ++ct) {
        const f16* wtp = Wt + (ct * 16 + ln15) * 128 + lg * 8;
#pragma unroll
        for (int s = 0; s < 4; ++s) {
            const f16x8 wb = *(const f16x8*)(wtp + s * 32);
            acc[ct] = __builtin_amdgcn_mfma_f32_16x16x32_f16(xa[s], wb, acc[ct], 0, 0, 0);
        }
    }

    const long grow0 = rowbase + wid * 16 + 4 * lg;
#pragma unroll
    for (int ct = 0; ct < 4; ++ct) {
        const int col = ct * 16 + ln15;
        const float b = bq[col] * LOG2E;
#pragma unroll
        for (int r = 0; r < 4; ++r)
            Q[(grow0 + r) * HH + col] = (f16)(acc[ct][r] + b);
    }
#pragma unroll
    for (int ct = 4; ct < 8; ++ct) {
        const int col = (ct - 4) * 16 + ln15;
        const float b = bk[col];
#pragma unroll
        for (int r = 0; r < 4; ++r)
            K[(grow0 + r) * HH + col] = (f16)(acc[ct][r] + b);
    }
    {
        const long batch = rowbase >> 12;
        const long inrow = (rowbase & 4095) + wid * 16 + 4 * lg;
#pragma unroll
        for (int ct = 8; ct < 12; ++ct) {
            const int o = (ct - 8) * 16 + ln15;
            const float b = bv[o];
            unsigned long long pk =
                (unsigned long long)pk2h(acc[ct][0] + b, acc[ct][1] + b) |
                ((unsigned long long)pk2h(acc[ct][2] + b, acc[ct][3] + b) << 32);
            *(unsigned long long*)(Vt + ((long)batch * HH + o) * SS + inrow) = pk;
        }
    }
}

// ---------------- MFMA flash attention, fp16, exp2-domain, split-K4 ----------------
// grid 2048 = 8 batch (XCD-affine) x 4 split x 64 qtile; 256 thr = 4 waves.
// Wave = 16 q rows. KV tile = 64 keys, double-buffered LDS, staged by
// global_load_lds DMA with pre-swizzled per-lane SOURCE addresses (linear
// LDS dest). m97 2-barrier loop: issue(t+1) -> compute(t) -> vmcnt(0)+bar.
// T13 defer-max, T5 setprio. Partials: normalized f16 O + log2-LSE.
__global__ __launch_bounds__(256, 4) void flash_kernel(
    const f16* __restrict__ Q, const f16* __restrict__ K,
    const f16* __restrict__ Vt, f16* __restrict__ Onorm,
    float* __restrict__ lse)
{
    __shared__ __align__(16) short k_s[2][64 * HH];   // 2 x 8 KB
    __shared__ __align__(16) short v_s[2][64 * HH];   // 2 x 8 KB  [o][key]
    __shared__ __align__(16) short p_s[4 * 16 * HH];  // 8 KB per-wave P

    const int tid  = threadIdx.x;
    const int lane = tid & 63;
    const int wid  = tid >> 6;
    const int ln15 = lane & 15;
    const int lg   = lane >> 4;
    const int batch = blockIdx.x & 7;
    const int rest  = blockIdx.x >> 3;
    const int split = rest & 3;
    const int qtile = rest >> 2;
    const int k0base = split * (SS / 4);

    // Q fragments (B-operand): col q = ln15, k = s*32 + lg*8 + j
    f16x8 qf[2];
    {
        const long qrow = (long)batch * SS + qtile * 64 + wid * 16 + ln15;
        const f16* qp = Q + qrow * HH + lg * 8;
        qf[0] = *(const f16x8*)(qp);
        qf[1] = *(const f16x8*)(qp + 32);
    }

    f32x4 oacc[4];
#pragma unroll
    for (int ot = 0; ot < 4; ++ot) oacc[ot] = (f32x4){0.f, 0.f, 0.f, 0.f};
    float m = -1e30f, l = 0.f;

    short* pw = p_s + wid * (16 * HH);
    const int swq = (ln15 & 7) << 4;

    // ---- DMA staging geometry ----
    // Tile = 8 KB = 8 chunks of 1 KB; wave `wid` owns chunks {2wid, 2wid+1}.
    // Within a chunk, lane l covers row (l>>3), col-chunk (l&7). The XOR
    // swizzle only permutes bits 4-6 (within-row), so it is applied to the
    // per-lane GLOBAL source address; LDS dest stays linear.
    const int crow = lane >> 3;                       // 0..7
    const int ccs  = ((lane & 7) * 16) ^ (crow << 4); // swizzled col bytes
    const int row0 = wid * 16 + crow;                 // rows row0, row0+8
    const char* kgb = (const char*)(K + ((long)batch * SS + k0base) * HH);
    const char* vgb = (const char*)(Vt + (long)batch * HH * SS);
    const long koff = (long)row0 * 128 + ccs;             // K rows contiguous
    const long voff = (long)row0 * (SS * 2) + k0base * 2 + ccs; // V rows strided

    auto issue = [&](int t, int b) __attribute__((always_inline)) {
        char* kl = (char*)k_s[b] + wid * 2048;
        char* vl = (char*)v_s[b] + wid * 2048;
        const char* kg = kgb + (long)t * (64 * 128) + koff;
        const char* vg = vgb + (long)t * 128 + voff;
        async_copy16(kl,        kg);
        async_copy16(kl + 1024, kg + 1024);            // rows +8
        async_copy16(vl,        vg);
        async_copy16(vl + 1024, vg + 8 * (SS * 2));    // rows +8
    };

    // compute one 64-key tile from buffer `cur` (literal 0/1 at call sites)
    auto compute = [&](int cur) __attribute__((always_inline)) {
        const short* ks = k_s[cur];
        const short* vs = v_s[cur];

        // ---- QK^T (swapped: A = K rows, B = Q), scores in log2 domain ----
        f32x4 sacc[4];
        __builtin_amdgcn_s_setprio(1);
#pragma unroll
        for (int kt = 0; kt < 4; ++kt) {
            f32x4 a = (f32x4){0.f, 0.f, 0.f, 0.f};
            const int key = kt * 16 + ln15;
            const int rb = key * 128, swz = (key & 7) << 4;
            const f16x8 ka0 = *(const f16x8*)((const char*)ks + ((rb + lg * 16) ^ swz));
            const f16x8 ka1 = *(const f16x8*)((const char*)ks + ((rb + lg * 16 + 64) ^ swz));
            a = __builtin_amdgcn_mfma_f32_16x16x32_f16(ka0, qf[0], a, 0, 0, 0);
            a = __builtin_amdgcn_mfma_f32_16x16x32_f16(ka1, qf[1], a, 0, 0, 0);
            sacc[kt] = a;
        }
        __builtin_amdgcn_s_setprio(0);

        // ---- online softmax (exp2 domain), defer-max thr = 8*log2e ----
        float t0 = fmaxf(fmaxf(sacc[0][0], sacc[0][1]), sacc[0][2]);
        float t1 = fmaxf(fmaxf(sacc[0][3], sacc[1][0]), sacc[1][1]);
        float t2 = fmaxf(fmaxf(sacc[1][2], sacc[1][3]), sacc[2][0]);
        float t3 = fmaxf(fmaxf(sacc[2][1], sacc[2][2]), sacc[2][3]);
        float t4 = fmaxf(fmaxf(sacc[3][0], sacc[3][1]), sacc[3][2]);
        float tm = fmaxf(fmaxf(fmaxf(t0, t1), t2), fmaxf(fmaxf(t3, t4), sacc[3][3]));
        tm = fmaxf(tm, __shfl_xor(tm, 16));
        tm = fmaxf(tm, __shfl_xor(tm, 32));
        if (!__all(tm <= m + 11.5f)) {
            const float mn = fmaxf(m, tm);
            const float alpha = __builtin_amdgcn_exp2f(m - mn);
            l *= alpha;
#pragma unroll
            for (int r = 0; r < 4; ++r) {
                const float ar = __shfl(alpha, lg * 4 + r);
                oacc[0][r] *= ar; oacc[1][r] *= ar;
                oacc[2][r] *= ar; oacc[3][r] *= ar;
            }
            m = mn;
        }

        float ps = 0.f;
#pragma unroll
        for (int kt = 0; kt < 4; ++kt)
#pragma unroll
            for (int r = 0; r < 4; ++r) {
                const float pv = __builtin_amdgcn_exp2f(sacc[kt][r] - m);
                sacc[kt][r] = pv;
                ps += pv;
            }
        ps += __shfl_xor(ps, 16);
        ps += __shfl_xor(ps, 32);
        l += ps;

        // P -> wave-private LDS: row q = ln15, key = 16kt + 4lg + r, b64 writes
#pragma unroll
        for (int kt = 0; kt < 4; ++kt) {
            uint2 pk;
            pk.x = pk2h(sacc[kt][0], sacc[kt][1]);
            pk.y = pk2h(sacc[kt][2], sacc[kt][3]);
            const int key = kt * 16 + lg * 4;
            *(uint2*)((char*)pw + ((ln15 * 128 + key * 2) ^ swq)) = pk;
        }

        // ---- O += P.V ----
        __builtin_amdgcn_s_setprio(1);
#pragma unroll
        for (int s = 0; s < 2; ++s) {
            const f16x8 pa = *(const f16x8*)((const char*)pw + ((ln15 * 128 + lg * 16 + s * 64) ^ swq));
#pragma unroll
            for (int ot = 0; ot < 4; ++ot) {
                const int o = ot * 16 + ln15;
                const f16x8 vb = *(const f16x8*)((const char*)vs + ((o * 128 + lg * 16 + s * 64) ^ ((o & 7) << 4)));
                oacc[ot] = __builtin_amdgcn_mfma_f32_16x16x32_f16(pa, vb, oacc[ot], 0, 0, 0);
            }
        }
        __builtin_amdgcn_s_setprio(0);
    };

    // prologue: DMA tile 0 into buf0, drain, sync
    issue(0, 0);
    vm_barrier();

    for (int t = 0; t < NT; t += 2) {
        issue(t + 1, 1);                 // DMA next tile while computing
        compute(0);
        vm_barrier();                    // t+1 loads had full compute to land
        if (t + 2 < NT) issue(t + 2, 0);
        compute(1);
        vm_barrier();
    }

    // epilogue: normalized f16 partials + log2-LSE
    const float linv = 1.0f / l;
    const long ridx = (long)split * (BB * SS) + (long)batch * SS + qtile * 64 + wid * 16;
#pragma unroll
    for (int r = 0; r < 4; ++r) {
        const float ir = __shfl(linv, lg * 4 + r);
        f16* op = Onorm + (ridx + lg * 4 + r) * HH + ln15;
        op[0]  = (f16)(oacc[0][r] * ir);
        op[16] = (f16)(oacc[1][r] * ir);
        op[32] = (f16)(oacc[2][r] * ir);
        op[48] = (f16)(oacc[3][r] * ir);
    }
    if (lg == 0)
        lse[ridx + ln15] = m + __builtin_amdgcn_logf(l);
}

// ---------------- split-K merge (log2-LSE weighted) ----------------
__global__ __launch_bounds__(256) void merge_kernel(
    const f16* __restrict__ Onorm, const float* __restrict__ lse,
    float* __restrict__ Out)
{
    const int gid = blockIdx.x * 256 + threadIdx.x;   // 32768 rows x 8 col-groups
    const long row = gid >> 3;
    const int c0 = (gid & 7) * 8;
    const long NR = (long)BB * SS;

    float ls[4];
#pragma unroll
    for (int i = 0; i < 4; ++i) ls[i] = lse[i * NR + row];
    const float M = fmaxf(fmaxf(ls[0], ls[1]), fmaxf(ls[2], ls[3]));
    float g[4], denom = 0.f;
#pragma unroll
    for (int i = 0; i < 4; ++i) { g[i] = __builtin_amdgcn_exp2f(ls[i] - M); denom += g[i]; }
    const float inv = 1.0f / denom;

    float acc[8];
#pragma unroll
    for (int j = 0; j < 8; ++j) acc[j] = 0.f;
#pragma unroll
    for (int i = 0; i < 4; ++i) {
        const f16x8 o = *(const f16x8*)(Onorm + (i * NR + row) * HH + c0);
#pragma unroll
        for (int j = 0; j < 8; ++j) acc[j] = fmaf(g[i], (float)o[j], acc[j]);
    }
    float4 r0, r1;
    r0.x = acc[0] * inv; r0.y = acc[1] * inv; r0.z = acc[2] * inv; r0.w = acc[3] * inv;
    r1.x = acc[4] * inv; r1.y = acc[5] * inv; r1.z = acc[6] * inv; r1.w = acc[7] * inv;
    float4* dst = (float4*)(Out + row * HH + c0);
    dst[0] = r0;
    dst[1] = r1;
}

extern "C" void kernel_launch(void* const* d_in, const int* in_sizes, int n_in,
                              void* d_out, int out_size, void* d_ws, size_t ws_size,
                              hipStream_t stream) {
    const float* x  = (const float*)d_in[0];
    const float* Wq = (const float*)d_in[1];
    const float* bq = (const float*)d_in[2];
    const float* Wk = (const float*)d_in[3];
    const float* bk = (const float*)d_in[4];
    const float* Wv = (const float*)d_in[5];
    const float* bv = (const float*)d_in[6];
    float* out = (float*)d_out;

    // ws: Q f16 4MB | K f16 4MB | Vt f16 4MB | Wt 48KB | Onorm f16 16MB | lse f32 512KB
    const size_t NTOK = (size_t)BB * SS;
    f16* Q  = (f16*)d_ws;
    f16* K  = Q + NTOK * HH;
    f16* Vt = K + NTOK * HH;
    f16* Wt = Vt + NTOK * HH;
    f16* Onorm = Wt + 192 * 128;
    float* lse = (float*)(Onorm + 4 * NTOK * HH);

    wtrans_kernel<<<96, 256, 0, stream>>>(Wq, Wk, Wv, Wt);
    qkv_kernel<<<BB * SS / 64, 256, 0, stream>>>(x, Wt, bq, bk, bv, Q, K, Vt);
    flash_kernel<<<BB * 4 * (SS / 64), 256, 0, stream>>>(Q, K, Vt, Onorm, lse);
    merge_kernel<<<BB * SS * 8 / 256, 256, 0, stream>>>(Onorm, lse, out);
}

// Round 7
// 81.926 us; speedup vs baseline: 1.1099x; 1.1099x over previous
//
#include <hip/hip_runtime.h>
#include <math.h>

#define BB 8
#define SS 4096
#define EE 128
#define HH 64
#define NT 16   // KV tiles per flash block (split-K4: 1024 keys / 64)
#define LOG2E 1.44269504088896f

typedef _Float16 f16;
typedef __attribute__((ext_vector_type(8))) _Float16 f16x8;
typedef __attribute__((ext_vector_type(4))) float f32x4;
typedef __attribute__((ext_vector_type(16))) float f32x16;
typedef __attribute__((ext_vector_type(4))) unsigned int u32x4;

__device__ __forceinline__ unsigned int pk2h(float a, float b) {
    return __builtin_bit_cast(unsigned int, __builtin_amdgcn_cvt_pkrtz(a, b));
}

// async global->LDS DMA, 16 B per lane (linear LDS dest; swizzle is applied
// to the per-lane GLOBAL source address -- m173 pattern / rule #21).
__device__ __forceinline__ void async_copy16(void* lds, const void* g) {
    __builtin_amdgcn_global_load_lds(
        (const __attribute__((address_space(1))) void*)g,
        (__attribute__((address_space(3))) void*)lds, 16, 0, 0);
}

// drain DMA + LDS, workgroup barrier, pin scheduler (rule #18)
__device__ __forceinline__ void vm_barrier() {
    asm volatile("s_waitcnt vmcnt(0) lgkmcnt(0)" ::: "memory");
    __builtin_amdgcn_s_barrier();
    __builtin_amdgcn_sched_barrier(0);
}

// ---------------- W transpose+convert setup ----------------
// Wt f16 [192 cols][128 e]: cols 0-63 = Wq*log2e, 64-127 = Wk, 128-191 = Wv.
__global__ __launch_bounds__(256) void wtrans_kernel(
    const float* __restrict__ Wq, const float* __restrict__ Wk,
    const float* __restrict__ Wv, f16* __restrict__ Wt)
{
    const int idx = blockIdx.x * 256 + threadIdx.x;
    if (idx >= 192 * 128) return;
    const int col = idx >> 7, e = idx & 127;
    const float v = (col < 64)  ? Wq[e * 64 + col] * LOG2E
                  : (col < 128) ? Wk[e * 64 + (col - 64)]
                                : Wv[e * 64 + (col - 128)];
    Wt[col * 128 + e] = (f16)v;
}

// ---------------- QKV projection: fp16 MFMA GEMM ----------------
// Q pre-scaled by log2e (folded into Wq/bq) -> flash softmax is exp2-native.
__global__ __launch_bounds__(256) void qkv_kernel(
    const float* __restrict__ x, const f16* __restrict__ Wt,
    const float* __restrict__ bq, const float* __restrict__ bk,
    const float* __restrict__ bv,
    f16* __restrict__ Q, f16* __restrict__ K, f16* __restrict__ Vt)
{
    __shared__ __align__(16) short xs[64 * EE];   // fp16 tile, 256 B rows
    const int tid = threadIdx.x;
    const long rowbase = (long)blockIdx.x * 64;

    {
        const float4* xg = (const float4*)(x + rowbase * EE);
#pragma unroll
        for (int j = 0; j < 8; ++j) {
            const int eidx = tid * 32 + j * 4;
            const float4 v = xg[eidx >> 2];
            unsigned long long pk =
                (unsigned long long)pk2h(v.x, v.y) |
                ((unsigned long long)pk2h(v.z, v.w) << 32);
            const int row = eidx >> 7;
            const int off = (row * 256 + (eidx & 127) * 2) ^ ((row & 7) << 4);
            *(unsigned long long*)((char*)xs + off) = pk;
        }
    }
    __syncthreads();

    const int lane = tid & 63;
    const int wid  = tid >> 6;
    const int ln15 = lane & 15;
    const int lg   = lane >> 4;

    f16x8 xa[4];
    {
        const int row = wid * 16 + ln15;
        const int swz = (row & 7) << 4;
#pragma unroll
        for (int s = 0; s < 4; ++s)
            xa[s] = *(const f16x8*)((const char*)xs + ((row * 256 + lg * 16 + s * 64) ^ swz));
    }

    f32x4 acc[12];
#pragma unroll
    for (int ct = 0; ct < 12; ++ct) acc[ct] = (f32x4){0.f, 0.f, 0.f, 0.f};

#pragma unroll
    for (int ct = 0; ct < 12; ++ct) {
        const f16* wtp = Wt + (ct * 16 + ln15) * 128 + lg * 8;
#pragma unroll
        for (int s = 0; s < 4; ++s) {
            const f16x8 wb = *(const f16x8*)(wtp + s * 32);
            acc[ct] = __builtin_amdgcn_mfma_f32_16x16x32_f16(xa[s], wb, acc[ct], 0, 0, 0);
        }
    }

    const long grow0 = rowbase + wid * 16 + 4 * lg;
#pragma unroll
    for (int ct = 0; ct < 4; ++ct) {
        const int col = ct * 16 + ln15;
        const float b = bq[col] * LOG2E;
#pragma unroll
        for (int r = 0; r < 4; ++r)
            Q[(grow0 + r) * HH + col] = (f16)(acc[ct][r] + b);
    }
#pragma unroll
    for (int ct = 4; ct < 8; ++ct) {
        const int col = (ct - 4) * 16 + ln15;
        const float b = bk[col];
#pragma unroll
        for (int r = 0; r < 4; ++r)
            K[(grow0 + r) * HH + col] = (f16)(acc[ct][r] + b);
    }
    {
        const long batch = rowbase >> 12;
        const long inrow = (rowbase & 4095) + wid * 16 + 4 * lg;
#pragma unroll
        for (int ct = 8; ct < 12; ++ct) {
            const int o = (ct - 8) * 16 + ln15;
            const float b = bv[o];
            unsigned long long pk =
                (unsigned long long)pk2h(acc[ct][0] + b, acc[ct][1] + b) |
                ((unsigned long long)pk2h(acc[ct][2] + b, acc[ct][3] + b) << 32);
            *(unsigned long long*)(Vt + ((long)batch * HH + o) * SS + inrow) = pk;
        }
    }
}

// ---------------- MFMA flash attention, 32x32 shape, O^T, split-K4 ----------------
// grid 1024 = 8 batch (XCD-affine) x 4 split x 32 qblk; 256 thr = 4 waves.
// Wave = 32 q rows (q = lane&31). KV tile = 64 keys, double-buffered LDS via
// global_load_lds DMA (pre-swizzled source). Swapped QK^T (32x32x16) puts q
// lane-local; P stays in REGISTERS (consistent-permutation trick: PV uses
// key->k-slot map pi(8*h5+j)=(j&3)+8*(j>>2)+4*h5 on BOTH operands, so the
// P B-frag is the lane's own packed regs and V A-frags are two b64 LDS
// reads). PV computes O^T so rescale/eplilogue are lane-local. T13 defer-max,
// T5 setprio. Partials: normalized f16 O + log2-LSE.
__global__ __launch_bounds__(256, 4) void flash_kernel(
    const f16* __restrict__ Q, const f16* __restrict__ K,
    const f16* __restrict__ Vt, f16* __restrict__ Onorm,
    float* __restrict__ lse)
{
    __shared__ __align__(16) short k_s[2][64 * HH];   // 2 x 8 KB
    __shared__ __align__(16) short v_s[2][64 * HH];   // 2 x 8 KB  [o][key]

    const int tid  = threadIdx.x;
    const int lane = tid & 63;
    const int wid  = tid >> 6;
    const int q31  = lane & 31;
    const int h5   = lane >> 5;
    const int batch = blockIdx.x & 7;
    const int split = (blockIdx.x >> 3) & 3;
    const int qblk  = blockIdx.x >> 5;
    const int k0base = split * (SS / 4);

    // Q B-frags: col q = q31, k-slot (h5)*8+j at dim 16*step + 8*h5 + j
    f16x8 qf[4];
    {
        const long qrow = (long)batch * SS + qblk * 128 + wid * 32 + q31;
        const f16* qp = Q + qrow * HH + 8 * h5;
        qf[0] = *(const f16x8*)(qp);
        qf[1] = *(const f16x8*)(qp + 16);
        qf[2] = *(const f16x8*)(qp + 32);
        qf[3] = *(const f16x8*)(qp + 48);
    }

    f32x16 oacc0 = {0.f,0.f,0.f,0.f,0.f,0.f,0.f,0.f,0.f,0.f,0.f,0.f,0.f,0.f,0.f,0.f};
    f32x16 oacc1 = oacc0;           // O^T rows o (+32), col q = q31
    float m = -1e30f, l = 0.f;

    // ---- DMA staging geometry (identical to R5) ----
    const int crow = lane >> 3;                       // 0..7
    const int ccs  = ((lane & 7) * 16) ^ (crow << 4); // swizzled col bytes
    const int row0 = wid * 16 + crow;                 // rows row0, row0+8
    const char* kgb = (const char*)(K + ((long)batch * SS + k0base) * HH);
    const char* vgb = (const char*)(Vt + (long)batch * HH * SS);
    const long koff = (long)row0 * 128 + ccs;
    const long voff = (long)row0 * (SS * 2) + k0base * 2 + ccs;

    auto issue = [&](int t, int b) __attribute__((always_inline)) {
        char* kl = (char*)k_s[b] + wid * 2048;
        char* vl = (char*)v_s[b] + wid * 2048;
        const char* kg = kgb + (long)t * (64 * 128) + koff;
        const char* vg = vgb + (long)t * 128 + voff;
        async_copy16(kl,        kg);
        async_copy16(kl + 1024, kg + 1024);            // rows +8
        async_copy16(vl,        vg);
        async_copy16(vl + 1024, vg + 8 * (SS * 2));    // rows +8
    };

    auto compute = [&](int cur) __attribute__((always_inline)) {
        const char* ks = (const char*)k_s[cur];
        const char* vs = (const char*)v_s[cur];

        // ---- QK^T: S^T[key][q] = mfma(A=K rows, B=Q cols), log2 domain ----
        f32x16 s0 = {0.f,0.f,0.f,0.f,0.f,0.f,0.f,0.f,0.f,0.f,0.f,0.f,0.f,0.f,0.f,0.f};
        f32x16 s1 = s0;
        __builtin_amdgcn_s_setprio(1);
#pragma unroll
        for (int step = 0; step < 4; ++step) {
            const int cb = step * 32 + 16 * h5;
            const int r0 = q31;
            const f16x8 ka0 = *(const f16x8*)(ks + ((r0 * 128 + cb) ^ ((r0 & 7) << 4)));
            s0 = __builtin_amdgcn_mfma_f32_32x32x16_f16(ka0, qf[step], s0, 0, 0, 0);
            const int r1 = q31 + 32;
            const f16x8 ka1 = *(const f16x8*)(ks + ((r1 * 128 + cb) ^ ((r1 & 7) << 4)));
            s1 = __builtin_amdgcn_mfma_f32_32x32x16_f16(ka1, qf[step], s1, 0, 0, 0);
        }
        __builtin_amdgcn_s_setprio(0);

        // ---- online softmax (exp2 domain), q lane-local, defer-max ----
        float tm = s0[0];
#pragma unroll
        for (int i = 1; i < 16; ++i) tm = fmaxf(tm, s0[i]);
#pragma unroll
        for (int i = 0; i < 16; ++i) tm = fmaxf(tm, s1[i]);
        tm = fmaxf(tm, __shfl_xor(tm, 32));
        if (!__all(tm <= m + 11.5f)) {
            const float mn = fmaxf(m, tm);
            const float alpha = __builtin_amdgcn_exp2f(m - mn);
            l *= alpha;
            oacc0 *= alpha;              // lane-local: O^T col = q
            oacc1 *= alpha;
            m = mn;
        }

        unsigned int pk[16];
        float ps = 0.f;
#pragma unroll
        for (int i = 0; i < 8; ++i) {
            const float a = __builtin_amdgcn_exp2f(s0[2 * i] - m);
            const float b = __builtin_amdgcn_exp2f(s0[2 * i + 1] - m);
            ps += a + b;
            pk[i] = pk2h(a, b);
        }
#pragma unroll
        for (int i = 0; i < 8; ++i) {
            const float a = __builtin_amdgcn_exp2f(s1[2 * i] - m);
            const float b = __builtin_amdgcn_exp2f(s1[2 * i + 1] - m);
            ps += a + b;
            pk[8 + i] = pk2h(a, b);
        }
        ps += __shfl_xor(ps, 32);
        l += ps;

        // ---- O^T += V^T . P  (A = V^T from LDS, B = P own regs) ----
        __builtin_amdgcn_s_setprio(1);
#pragma unroll
        for (int mb = 0; mb < 4; ++mb) {
            const u32x4 pw = {pk[4 * mb], pk[4 * mb + 1], pk[4 * mb + 2], pk[4 * mb + 3]};
            const f16x8 pb = __builtin_bit_cast(f16x8, pw);
            const int cb_lo = 32 * mb + 8 * h5;
#pragma unroll
            for (int oh = 0; oh < 2; ++oh) {
                const int row = q31 + 32 * oh;
                const int swz = (row & 7) << 4;
                const uint2 lo = *(const uint2*)(vs + ((row * 128 + cb_lo) ^ swz));
                const uint2 hi = *(const uint2*)(vs + ((row * 128 + cb_lo + 16) ^ swz));
                const u32x4 w = {lo.x, lo.y, hi.x, hi.y};
                const f16x8 va = __builtin_bit_cast(f16x8, w);
                if (oh == 0)
                    oacc0 = __builtin_amdgcn_mfma_f32_32x32x16_f16(va, pb, oacc0, 0, 0, 0);
                else
                    oacc1 = __builtin_amdgcn_mfma_f32_32x32x16_f16(va, pb, oacc1, 0, 0, 0);
            }
        }
        __builtin_amdgcn_s_setprio(0);
    };

    // prologue: DMA tile 0 into buf0, drain, sync
    issue(0, 0);
    vm_barrier();

    for (int t = 0; t < NT; t += 2) {
        issue(t + 1, 1);
        compute(0);
        vm_barrier();
        if (t + 2 < NT) issue(t + 2, 0);
        compute(1);
        vm_barrier();
    }

    // epilogue: normalized f16 partials (O^T scatter) + log2-LSE
    const float linv = 1.0f / l;
    const long tok = (long)split * (BB * SS) + (long)batch * SS + qblk * 128 + wid * 32 + q31;
    f16* ob = Onorm + tok * HH;
#pragma unroll
    for (int i = 0; i < 16; ++i) {
        const int od = (i & 3) + 8 * (i >> 2) + 4 * h5;
        ob[od]      = (f16)(oacc0[i] * linv);
        ob[od + 32] = (f16)(oacc1[i] * linv);
    }
    if (h5 == 0)
        lse[tok] = m + __builtin_amdgcn_logf(l);
}

// ---------------- split-K merge (log2-LSE weighted) ----------------
__global__ __launch_bounds__(256) void merge_kernel(
    const f16* __restrict__ Onorm, const float* __restrict__ lse,
    float* __restrict__ Out)
{
    const int gid = blockIdx.x * 256 + threadIdx.x;   // 32768 rows x 8 col-groups
    const long row = gid >> 3;
    const int c0 = (gid & 7) * 8;
    const long NR = (long)BB * SS;

    float ls[4];
#pragma unroll
    for (int i = 0; i < 4; ++i) ls[i] = lse[i * NR + row];
    const float M = fmaxf(fmaxf(ls[0], ls[1]), fmaxf(ls[2], ls[3]));
    float g[4], denom = 0.f;
#pragma unroll
    for (int i = 0; i < 4; ++i) { g[i] = __builtin_amdgcn_exp2f(ls[i] - M); denom += g[i]; }
    const float inv = 1.0f / denom;

    float acc[8];
#pragma unroll
    for (int j = 0; j < 8; ++j) acc[j] = 0.f;
#pragma unroll
    for (int i = 0; i < 4; ++i) {
        const f16x8 o = *(const f16x8*)(Onorm + (i * NR + row) * HH + c0);
#pragma unroll
        for (int j = 0; j < 8; ++j) acc[j] = fmaf(g[i], (float)o[j], acc[j]);
    }
    float4 r0, r1;
    r0.x = acc[0] * inv; r0.y = acc[1] * inv; r0.z = acc[2] * inv; r0.w = acc[3] * inv;
    r1.x = acc[4] * inv; r1.y = acc[5] * inv; r1.z = acc[6] * inv; r1.w = acc[7] * inv;
    float4* dst = (float4*)(Out + row * HH + c0);
    dst[0] = r0;
    dst[1] = r1;
}

extern "C" void kernel_launch(void* const* d_in, const int* in_sizes, int n_in,
                              void* d_out, int out_size, void* d_ws, size_t ws_size,
                              hipStream_t stream) {
    const float* x  = (const float*)d_in[0];
    const float* Wq = (const float*)d_in[1];
    const float* bq = (const float*)d_in[2];
    const float* Wk = (const float*)d_in[3];
    const float* bk = (const float*)d_in[4];
    const float* Wv = (const float*)d_in[5];
    const float* bv = (const float*)d_in[6];
    float* out = (float*)d_out;

    // ws: Q f16 4MB | K f16 4MB | Vt f16 4MB | Wt 48KB | Onorm f16 16MB | lse f32 512KB
    const size_t NTOK = (size_t)BB * SS;
    f16* Q  = (f16*)d_ws;
    f16* K  = Q + NTOK * HH;
    f16* Vt = K + NTOK * HH;
    f16* Wt = Vt + NTOK * HH;
    f16* Onorm = Wt + 192 * 128;
    float* lse = (float*)(Onorm + 4 * NTOK * HH);

    wtrans_kernel<<<96, 256, 0, stream>>>(Wq, Wk, Wv, Wt);
    qkv_kernel<<<BB * SS / 64, 256, 0, stream>>>(x, Wt, bq, bk, bv, Q, K, Vt);
    flash_kernel<<<BB * 4 * (SS / 128), 256, 0, stream>>>(Q, K, Vt, Onorm, lse);
    merge_kernel<<<BB * SS * 8 / 256, 256, 0, stream>>>(Onorm, lse, out);
}

// Round 9
// 78.112 us; speedup vs baseline: 1.1641x; 1.0488x over previous
//
#include <hip/hip_runtime.h>
#include <math.h>

#define BB 8
#define SS 4096
#define EE 128
#define HH 64
#define NT 16   // KV tiles per flash block (split-K4: 1024 keys / 64)
#define LOG2E 1.44269504088896f

typedef _Float16 f16;
typedef __attribute__((ext_vector_type(8))) _Float16 f16x8;
typedef __attribute__((ext_vector_type(4))) float f32x4;
typedef __attribute__((ext_vector_type(16))) float f32x16;
typedef __attribute__((ext_vector_type(4))) unsigned int u32x4;

__device__ __forceinline__ unsigned int pk2h(float a, float b) {
    return __builtin_bit_cast(unsigned int, __builtin_amdgcn_cvt_pkrtz(a, b));
}

// async global->LDS DMA, 16 B per lane (linear LDS dest; swizzle is applied
// to the per-lane GLOBAL source address -- m173 pattern / rule #21).
__device__ __forceinline__ void async_copy16(void* lds, const void* g) {
    __builtin_amdgcn_global_load_lds(
        (const __attribute__((address_space(1))) void*)g,
        (__attribute__((address_space(3))) void*)lds, 16, 0, 0);
}

// ALL-WAVES buffer handoff: per-wave vmcnt(0)+lgkmcnt(0) then s_barrier.
// vmcnt is per-wave, so the barrier is what makes every wave's DMA chunk
// visible to every reader (R7's race: dropping the barrier here).
__device__ __forceinline__ void vm_barrier() {
    asm volatile("s_waitcnt vmcnt(0) lgkmcnt(0)" ::: "memory");
    __builtin_amdgcn_s_barrier();
    __builtin_amdgcn_sched_barrier(0);
}

// ---------------- W transpose+convert setup ----------------
// Wt f16 [192 cols][128 e]: cols 0-63 = Wq*log2e, 64-127 = Wk, 128-191 = Wv.
__global__ __launch_bounds__(256) void wtrans_kernel(
    const float* __restrict__ Wq, const float* __restrict__ Wk,
    const float* __restrict__ Wv, f16* __restrict__ Wt)
{
    const int idx = blockIdx.x * 256 + threadIdx.x;
    if (idx >= 192 * 128) return;
    const int col = idx >> 7, e = idx & 127;
    const float v = (col < 64)  ? Wq[e * 64 + col] * LOG2E
                  : (col < 128) ? Wk[e * 64 + (col - 64)]
                                : Wv[e * 64 + (col - 128)];
    Wt[col * 128 + e] = (f16)v;
}

// ---------------- QKV projection: fp16 MFMA GEMM, no LDS ----------------
// A-frags read directly from global x (per-(row,s) the 4 lg-lanes cover a
// contiguous 128B chunk -> coalesced; x read exactly once, L2-backed).
// Q pre-scaled by log2e. Vt written with sigma-permuted key index (swap
// bits 2<->3 of the low nibble) so flash PV fragments are single b128 reads.
__global__ __launch_bounds__(256) void qkv_kernel(
    const float* __restrict__ x, const f16* __restrict__ Wt,
    const float* __restrict__ bq, const float* __restrict__ bk,
    const float* __restrict__ bv,
    f16* __restrict__ Q, f16* __restrict__ K, f16* __restrict__ Vt)
{
    const int tid  = threadIdx.x;
    const int lane = tid & 63;
    const int wid  = tid >> 6;
    const int ln15 = lane & 15;
    const int lg   = lane >> 4;
    const long rowbase = (long)blockIdx.x * 64;

    // A fragments: row = wid*16 + ln15, dim = s*32 + lg*8 + j
    f16x8 xa[4];
    {
        const float* xp = x + (rowbase + wid * 16 + ln15) * EE + lg * 8;
#pragma unroll
        for (int s = 0; s < 4; ++s) {
            const float4 u = *(const float4*)(xp + s * 32);
            const float4 v = *(const float4*)(xp + s * 32 + 4);
            const u32x4 w = {pk2h(u.x, u.y), pk2h(u.z, u.w),
                             pk2h(v.x, v.y), pk2h(v.z, v.w)};
            xa[s] = __builtin_bit_cast(f16x8, w);
        }
    }

    f32x4 acc[12];
#pragma unroll
    for (int ct = 0; ct < 12; ++ct) acc[ct] = (f32x4){0.f, 0.f, 0.f, 0.f};

#pragma unroll
    for (int ct = 0; ct < 12; ++ct) {
        const f16* wtp = Wt + (ct * 16 + ln15) * 128 + lg * 8;
#pragma unroll
        for (int s = 0; s < 4; ++s) {
            const f16x8 wb = *(const f16x8*)(wtp + s * 32);
            acc[ct] = __builtin_amdgcn_mfma_f32_16x16x32_f16(xa[s], wb, acc[ct], 0, 0, 0);
        }
    }

    const long grow0 = rowbase + wid * 16 + 4 * lg;
#pragma unroll
    for (int ct = 0; ct < 4; ++ct) {
        const int col = ct * 16 + ln15;
        const float b = bq[col] * LOG2E;
#pragma unroll
        for (int r = 0; r < 4; ++r)
            Q[(grow0 + r) * HH + col] = (f16)(acc[ct][r] + b);
    }
#pragma unroll
    for (int ct = 4; ct < 8; ++ct) {
        const int col = (ct - 4) * 16 + ln15;
        const float b = bk[col];
#pragma unroll
        for (int r = 0; r < 4; ++r)
            K[(grow0 + r) * HH + col] = (f16)(acc[ct][r] + b);
    }
    {
        const long batch = rowbase >> 12;
        // sigma-permuted key index: swap bits 2<->3 of the low nibble.
        // key&15 = 4*lg + r  ->  pos&15 = 8*(lg&1) + 4*(lg>>1) + r
        // (the 4-run over r stays contiguous -> one 8B store).
        const long inrow0 = (rowbase & 4095) + wid * 16;
        const long inrowP = inrow0 + 8 * (lg & 1) + 4 * (lg >> 1);
#pragma unroll
        for (int ct = 8; ct < 12; ++ct) {
            const int o = (ct - 8) * 16 + ln15;
            const float b = bv[o];
            unsigned long long pk =
                (unsigned long long)pk2h(acc[ct][0] + b, acc[ct][1] + b) |
                ((unsigned long long)pk2h(acc[ct][2] + b, acc[ct][3] + b) << 32);
            *(unsigned long long*)(Vt + ((long)batch * HH + o) * SS + inrowP) = pk;
        }
    }
}

// ---------------- MFMA flash attention, 32x32, O^T, split-K4 ----------------
// grid 1024 = 8 batch (XCD-affine) x 4 split x 32 qblk; 256 thr = 4 waves.
// Wave = 32 q rows (q = lane&31). KV tile = 64 keys, double-buffered LDS via
// global_load_lds DMA (pre-swizzled source). Swapped QK^T (32x32x16) puts q
// lane-local; P stays in REGISTERS (consistent-permutation trick) and the
// sigma-permuted Vt makes each PV A-frag ONE b128 LDS read (same access form
// as the K-side reads -> conflict-free). PV computes O^T so rescale/epilogue
// are lane-local. R6's proven issue->compute->vm_barrier loop (1 bar/tile).
__global__ __launch_bounds__(256, 4) void flash_kernel(
    const f16* __restrict__ Q, const f16* __restrict__ K,
    const f16* __restrict__ Vt, f16* __restrict__ Onorm,
    float* __restrict__ lse)
{
    __shared__ __align__(16) short k_s[2][64 * HH];   // 2 x 8 KB
    __shared__ __align__(16) short v_s[2][64 * HH];   // 2 x 8 KB  [o][key-perm]

    const int tid  = threadIdx.x;
    const int lane = tid & 63;
    const int wid  = tid >> 6;
    const int q31  = lane & 31;
    const int h5   = lane >> 5;
    const int batch = blockIdx.x & 7;
    const int split = (blockIdx.x >> 3) & 3;
    const int qblk  = blockIdx.x >> 5;
    const int k0base = split * (SS / 4);

    // Q B-frags: col q = q31, k-slot 8h5+j at dim 16*step + 8*h5 + j
    f16x8 qf[4];
    {
        const long qrow = (long)batch * SS + qblk * 128 + wid * 32 + q31;
        const f16* qp = Q + qrow * HH + 8 * h5;
        qf[0] = *(const f16x8*)(qp);
        qf[1] = *(const f16x8*)(qp + 16);
        qf[2] = *(const f16x8*)(qp + 32);
        qf[3] = *(const f16x8*)(qp + 48);
    }

    f32x16 oacc0 = {0.f,0.f,0.f,0.f,0.f,0.f,0.f,0.f,0.f,0.f,0.f,0.f,0.f,0.f,0.f,0.f};
    f32x16 oacc1 = oacc0;           // O^T rows o (+32), col q = q31
    float m = -1e30f, l = 0.f;

    // ---- DMA staging geometry ----
    const int crow = lane >> 3;                       // 0..7
    const int ccs  = ((lane & 7) * 16) ^ (crow << 4); // swizzled col bytes
    const int row0 = wid * 16 + crow;                 // rows row0, row0+8
    const char* kgb = (const char*)(K + ((long)batch * SS + k0base) * HH);
    const char* vgb = (const char*)(Vt + (long)batch * HH * SS);
    const long koff = (long)row0 * 128 + ccs;
    const long voff = (long)row0 * (SS * 2) + k0base * 2 + ccs;

    auto issue = [&](int t, int b) __attribute__((always_inline)) {
        char* kl = (char*)k_s[b] + wid * 2048;
        char* vl = (char*)v_s[b] + wid * 2048;
        const char* kg = kgb + (long)t * (64 * 128) + koff;
        const char* vg = vgb + (long)t * 128 + voff;
        async_copy16(kl,        kg);
        async_copy16(kl + 1024, kg + 1024);            // rows +8
        async_copy16(vl,        vg);
        async_copy16(vl + 1024, vg + 8 * (SS * 2));    // rows +8
    };

    // compute one 64-key tile from buffer `cur` (literal 0/1 at call sites)
    auto compute = [&](int cur) __attribute__((always_inline)) {
        const char* ks = (const char*)k_s[cur];
        const char* vs = (const char*)v_s[cur];

        // ---- QK^T: S^T[key][q] = mfma(A=K rows, B=Q cols), log2 domain ----
        f32x16 s0 = {0.f,0.f,0.f,0.f,0.f,0.f,0.f,0.f,0.f,0.f,0.f,0.f,0.f,0.f,0.f,0.f};
        f32x16 s1 = s0;
        __builtin_amdgcn_s_setprio(1);
#pragma unroll
        for (int step = 0; step < 4; ++step) {
            const int cb = step * 32 + 16 * h5;
            const int r0 = q31;
            const f16x8 ka0 = *(const f16x8*)(ks + ((r0 * 128 + cb) ^ ((r0 & 7) << 4)));
            s0 = __builtin_amdgcn_mfma_f32_32x32x16_f16(ka0, qf[step], s0, 0, 0, 0);
            const int r1 = q31 + 32;
            const f16x8 ka1 = *(const f16x8*)(ks + ((r1 * 128 + cb) ^ ((r1 & 7) << 4)));
            s1 = __builtin_amdgcn_mfma_f32_32x32x16_f16(ka1, qf[step], s1, 0, 0, 0);
        }
        __builtin_amdgcn_s_setprio(0);

        // ---- online softmax (exp2 domain), q lane-local, defer-max ----
        float tm = s0[0];
#pragma unroll
        for (int i = 1; i < 16; ++i) tm = fmaxf(tm, s0[i]);
#pragma unroll
        for (int i = 0; i < 16; ++i) tm = fmaxf(tm, s1[i]);
        tm = fmaxf(tm, __shfl_xor(tm, 32));
        if (!__all(tm <= m + 11.5f)) {
            const float mn = fmaxf(m, tm);
            const float alpha = __builtin_amdgcn_exp2f(m - mn);
            l *= alpha;
            oacc0 *= alpha;              // lane-local: O^T col = q
            oacc1 *= alpha;
            m = mn;
        }

        unsigned int pk[16];
        float ps = 0.f;
#pragma unroll
        for (int i = 0; i < 8; ++i) {
            const float a = __builtin_amdgcn_exp2f(s0[2 * i] - m);
            const float b = __builtin_amdgcn_exp2f(s0[2 * i + 1] - m);
            ps += a + b;
            pk[i] = pk2h(a, b);
        }
#pragma unroll
        for (int i = 0; i < 8; ++i) {
            const float a = __builtin_amdgcn_exp2f(s1[2 * i] - m);
            const float b = __builtin_amdgcn_exp2f(s1[2 * i + 1] - m);
            ps += a + b;
            pk[8 + i] = pk2h(a, b);
        }
        ps += __shfl_xor(ps, 32);
        l += ps;

        // ---- O^T += V^T . P  (A = V^T single b128, sigma-permuted; B = P regs) ----
        __builtin_amdgcn_s_setprio(1);
#pragma unroll
        for (int mb = 0; mb < 4; ++mb) {
            const u32x4 pw = {pk[4 * mb], pk[4 * mb + 1], pk[4 * mb + 2], pk[4 * mb + 3]};
            const f16x8 pb = __builtin_bit_cast(f16x8, pw);
            const int cb = 32 * mb + 16 * h5;
#pragma unroll
            for (int oh = 0; oh < 2; ++oh) {
                const int row = q31 + 32 * oh;
                const f16x8 va = *(const f16x8*)(vs + ((row * 128 + cb) ^ ((row & 7) << 4)));
                if (oh == 0)
                    oacc0 = __builtin_amdgcn_mfma_f32_32x32x16_f16(va, pb, oacc0, 0, 0, 0);
                else
                    oacc1 = __builtin_amdgcn_mfma_f32_32x32x16_f16(va, pb, oacc1, 0, 0, 0);
            }
        }
        __builtin_amdgcn_s_setprio(0);
    };

    // prologue: DMA tile 0 into buf0, drain, sync
    issue(0, 0);
    vm_barrier();

    for (int t = 0; t < NT; t += 2) {
        issue(t + 1, 1);                 // DMA next tile while computing
        compute(0);
        vm_barrier();                    // t+1 loads had full compute to land
        if (t + 2 < NT) issue(t + 2, 0);
        compute(1);
        vm_barrier();
    }

    // epilogue: normalized f16 partials (O^T scatter) + log2-LSE
    const float linv = 1.0f / l;
    const long tok = (long)split * (BB * SS) + (long)batch * SS + qblk * 128 + wid * 32 + q31;
    f16* ob = Onorm + tok * HH;
#pragma unroll
    for (int i = 0; i < 16; ++i) {
        const int od = (i & 3) + 8 * (i >> 2) + 4 * h5;
        ob[od]      = (f16)(oacc0[i] * linv);
        ob[od + 32] = (f16)(oacc1[i] * linv);
    }
    if (h5 == 0)
        lse[tok] = m + __builtin_amdgcn_logf(l);
}

// ---------------- split-K merge (log2-LSE weighted) ----------------
__global__ __launch_bounds__(256) void merge_kernel(
    const f16* __restrict__ Onorm, const float* __restrict__ lse,
    float* __restrict__ Out)
{
    const int gid = blockIdx.x * 256 + threadIdx.x;   // 32768 rows x 8 col-groups
    const long row = gid >> 3;
    const int c0 = (gid & 7) * 8;
    const long NR = (long)BB * SS;

    float ls[4];
#pragma unroll
    for (int i = 0; i < 4; ++i) ls[i] = lse[i * NR + row];
    const float M = fmaxf(fmaxf(ls[0], ls[1]), fmaxf(ls[2], ls[3]));
    float g[4], denom = 0.f;
#pragma unroll
    for (int i = 0; i < 4; ++i) { g[i] = __builtin_amdgcn_exp2f(ls[i] - M); denom += g[i]; }
    const float inv = 1.0f / denom;

    float acc[8];
#pragma unroll
    for (int j = 0; j < 8; ++j) acc[j] = 0.f;
#pragma unroll
    for (int i = 0; i < 4; ++i) {
        const f16x8 o = *(const f16x8*)(Onorm + (i * NR + row) * HH + c0);
#pragma unroll
        for (int j = 0; j < 8; ++j) acc[j] = fmaf(g[i], (float)o[j], acc[j]);
    }
    float4 r0, r1;
    r0.x = acc[0] * inv; r0.y = acc[1] * inv; r0.z = acc[2] * inv; r0.w = acc[3] * inv;
    r1.x = acc[4] * inv; r1.y = acc[5] * inv; r1.z = acc[6] * inv; r1.w = acc[7] * inv;
    float4* dst = (float4*)(Out + row * HH + c0);
    dst[0] = r0;
    dst[1] = r1;
}

extern "C" void kernel_launch(void* const* d_in, const int* in_sizes, int n_in,
                              void* d_out, int out_size, void* d_ws, size_t ws_size,
                              hipStream_t stream) {
    const float* x  = (const float*)d_in[0];
    const float* Wq = (const float*)d_in[1];
    const float* bq = (const float*)d_in[2];
    const float* Wk = (const float*)d_in[3];
    const float* bk = (const float*)d_in[4];
    const float* Wv = (const float*)d_in[5];
    const float* bv = (const float*)d_in[6];
    float* out = (float*)d_out;

    // ws: Q f16 4MB | K f16 4MB | Vt f16 4MB | Wt 48KB | Onorm f16 16MB | lse f32 512KB
    const size_t NTOK = (size_t)BB * SS;
    f16* Q  = (f16*)d_ws;
    f16* K  = Q + NTOK * HH;
    f16* Vt = K + NTOK * HH;
    f16* Wt = Vt + NTOK * HH;
    f16* Onorm = Wt + 192 * 128;
    float* lse = (float*)(Onorm + 4 * NTOK * HH);

    wtrans_kernel<<<96, 256, 0, stream>>>(Wq, Wk, Wv, Wt);
    qkv_kernel<<<BB * SS / 64, 256, 0, stream>>>(x, Wt, bq, bk, bv, Q, K, Vt);
    flash_kernel<<<BB * 4 * (SS / 128), 256, 0, stream>>>(Q, K, Vt, Onorm, lse);
    merge_kernel<<<BB * SS * 8 / 256, 256, 0, stream>>>(Onorm, lse, out);
}